// Round 13
// baseline (43.178 us; speedup 1.0000x reference)
//
#include <hip/hip_runtime.h>

#define NN   32
#define HID  64

typedef __attribute__((ext_vector_type(8))) short bf16x8;
typedef __attribute__((ext_vector_type(4))) float f32x4;
typedef unsigned short u16;
typedef unsigned int   u32;

__device__ __forceinline__ float leaky(float v) { return v >= 0.f ? v : 0.01f * v; }
__device__ __forceinline__ float wsum64(float p) {
#pragma unroll
    for (int o = 32; o; o >>= 1) p += __shfl_xor(p, o);
    return p;
}
__device__ __forceinline__ u16 f2bf(float f) {
    union { float f; u32 u; } v; v.f = f;
    return (u16)((v.u + 0x7FFFu + ((v.u >> 16) & 1)) >> 16);
}
__device__ __forceinline__ float bf2f(short s) {
    union { u32 u; float f; } v; v.u = ((u32)(u16)s) << 16;
    return v.f;
}
__device__ __forceinline__ bf16x8 pack8(const float* v) {
    bf16x8 r;
#pragma unroll
    for (int e = 0; e < 8; ++e) r[e] = (short)f2bf(v[e]);
    return r;
}
// swizzled offsets: [row][64] and [row][32] bf16 tiles
__device__ __forceinline__ int swz(int row, int col)   { return row * 64 + ((((col >> 3) ^ (row & 7)) << 3) | (col & 7)); }
__device__ __forceinline__ int swz32(int row, int col) { return row * 32 + ((((col >> 3) ^ (row & 3)) << 3) | (col & 7)); }

// C += A(16xK=64) @ W(cols): A,W both swizzled bf16 tiles (LDS or global)
__device__ __forceinline__ f32x4 gemm64(f32x4 C, const u16* A, const u16* W, int lm, int kb8, int bcol) {
#pragma unroll
    for (int k0 = 0; k0 < 64; k0 += 32) {
        const int g = (k0 >> 3) + kb8;
        const bf16x8 a = *(const bf16x8*)&A[lm * 64 + ((g ^ (lm & 7)) << 3)];
        const bf16x8 w = *(const bf16x8*)&W[bcol * 64 + ((g ^ (bcol & 7)) << 3)];
        C = __builtin_amdgcn_mfma_f32_16x16x32_bf16(a, w, C, 0, 0, 0);
    }
    return C;
}
// C += A(16xK=32) @ W  (K=32 part tiles, zero-padded)
__device__ __forceinline__ f32x4 gemm32(f32x4 C, const u16* A, const u16* W, int lm, int kb8, int bcol) {
    const bf16x8 a = *(const bf16x8*)&A[lm * 32 + ((kb8 ^ (lm & 3)) << 3)];
    const bf16x8 w = *(const bf16x8*)&W[bcol * 32 + ((kb8 ^ (bcol & 3)) << 3)];
    return __builtin_amdgcn_mfma_f32_16x16x32_bf16(a, w, C, 0, 0, 0);
}

// weight-tile offsets (u16 units) inside wt arena
#define W_KW1  0
#define W_KW2  4096
#define W_QW1  8192
#define W_QW2  12288
#define W_KO1A 16384
#define W_KO2  20480
#define W_QO2  24576
#define W_QO1A 28672
#define W_AV1A 32768
#define W_FV1A 36864
#define W_KO1B 40960
#define W_QO1B 43008
#define W_AV1B 45056

// ---------------- kernel 0: weight prep (bf16 swizzled W^T) + MT/c ----------------
__global__ __launch_bounds__(256)
void prep_kernel(const float* __restrict__ av2_w, const float* __restrict__ av2_b,
                 const float* __restrict__ fv1_w,
                 const float* __restrict__ kw1_w, const float* __restrict__ kw2_w,
                 const float* __restrict__ qw1_w, const float* __restrict__ qw2_w,
                 const float* __restrict__ ko1_w, const float* __restrict__ ko2_w,
                 const float* __restrict__ qo2_w, const float* __restrict__ qo1_w,
                 const float* __restrict__ av1_w,
                 u16* __restrict__ MT, float* __restrict__ c, u16* __restrict__ wt)
{
    const int blk = blockIdx.x, t = threadIdx.x;
    if (blk == 0) {
        // MT[h][k] = (av2_w @ fv1b)[k][h] bf16 swizzled ; c = av2_b @ fv1b
        const int h = t & 63, jg = t >> 6;
        __shared__ float sA[4096];
        for (int i = t; i < 4096; i += 256) sA[i] = av2_w[i];
        __syncthreads();
        const float* W = fv1_w + 4096;
        float acc[16];
#pragma unroll
        for (int i = 0; i < 16; ++i) acc[i] = 0.f;
        for (int m = 0; m < 64; ++m) {
            const float w = W[m * 64 + h];
#pragma unroll
            for (int i = 0; i < 16; ++i)
                acc[i] = fmaf(sA[(jg + 4 * i) * 64 + m], w, acc[i]);
        }
#pragma unroll
        for (int i = 0; i < 16; ++i) { const int k = jg + 4 * i; MT[swz(h, k)] = f2bf(acc[i]); }
        if (t < 64) {
            float s = 0.f;
            for (int m = 0; m < 64; ++m) s = fmaf(av2_b[m], W[m * 64 + t], s);
            c[t] = s;
        }
    } else if (blk <= 9) {
        // standard forward layers: Wtile[h][k] = W[k][h]  (transposed)
        const float* srcs[9] = {kw1_w, kw2_w, qw1_w, qw2_w, ko1_w, ko2_w, qo1_w, av1_w, fv1_w};
        const int    offs[9] = {W_KW1, W_KW2, W_QW1, W_QW2, W_KO1A, W_KO2, W_QO1A, W_AV1A, W_FV1A};
        const float* W = srcs[blk - 1]; u16* dst = wt + offs[blk - 1];
        for (int i = t; i < 4096; i += 256) { const int k = i >> 6, h = i & 63; dst[swz(h, k)] = f2bf(W[i]); }
    } else if (blk == 10) {
        // kq path needs the TRANSPOSED product: Wtile[h][d] = qo2_w[h][d]  (identity orientation)
        u16* dst = wt + W_QO2;
        for (int i = t; i < 4096; i += 256) { const int h = i >> 6, d = i & 63; dst[swz(h, d)] = f2bf(qo2_w[i]); }
    } else if (blk <= 13) {
        const float* srcs[3] = {ko1_w + 4096, qo1_w + 4096, av1_w + 4096};
        const int    offs[3] = {W_KO1B, W_QO1B, W_AV1B};
        const float* W = srcs[blk - 11]; u16* dst = wt + offs[blk - 11];
        for (int i = t; i < 1024; i += 256) {
            const int k = i >> 6, h = i & 63;
            dst[swz32(h, k)]      = f2bf(W[i]);
            dst[swz32(h, 16 + k)] = 0;
        }
    }
}

// ---------------- kernel 1: MFMA setup (256 blocks x 16 rows) ----------------
__global__ __launch_bounds__(256)
void setup_kernel(const float* __restrict__ states, const float* __restrict__ policies,
                  const float* __restrict__ actions,
                  const float* __restrict__ kw1_b, const float* __restrict__ kw2_b,
                  const float* __restrict__ qw1_b, const float* __restrict__ qw2_b,
                  const float* __restrict__ ko1_b, const float* __restrict__ ko2_b,
                  const float* __restrict__ qo1_b, const float* __restrict__ qo2_b,
                  const float* __restrict__ av1_b, const float* __restrict__ fv1_b,
                  const u16* __restrict__ wt, const u16* __restrict__ MT,
                  const float* __restrict__ c_,
                  u32* __restrict__ kzg, u32* __restrict__ qzg,
                  float* __restrict__ kq, float* __restrict__ kb,
                  float* __restrict__ baseq, float* __restrict__ deltaq,
                  float* __restrict__ basev, float* __restrict__ deltav,
                  float* __restrict__ pre, float* __restrict__ vpf)
{
    const int blk = blockIdx.x;         // 256 blocks
    const int row0 = blk * 16;          // 16 global rows each
    const int t = threadIdx.x, lane = t & 63, jg = t >> 6;
    const int lm = lane & 15, kb8 = lane >> 4, cg = jg * 16 + lm;

    __shared__ __align__(16) u16 aST[1024], aH1[1024], aH2[1024], aKZ[1024], aQZ[1024];
    __shared__ __align__(16) u16 aP2[512], aDAP[512];
    __shared__ float fACT[256], fPOL[256];
    __shared__ float fKOBS[16 * 68];
    __shared__ float wzd[16];

    // ---- P0: stage inputs ----
    {
        const int i = t * 4, row = i >> 6, col = i & 63;
        const float4 s4 = *(const float4*)&states[row0 * 64 + i];
        const int base = swz(row, col);
        aST[base + 0] = f2bf(s4.x); aST[base + 1] = f2bf(s4.y);
        aST[base + 2] = f2bf(s4.z); aST[base + 3] = f2bf(s4.w);
        const float av = actions[row0 * 16 + t], pv = policies[row0 * 16 + t];
        fACT[t] = av; fPOL[t] = pv;
        const int r2 = t >> 4, cc = t & 15;
        aDAP[swz32(r2, cc)]      = f2bf(av - pv);
        aDAP[swz32(r2, 16 + cc)] = 0;
        aP2 [swz32(r2, 16 + cc)] = 0;
    }
    __syncthreads();

    // ---- P1: H = leaky(ST@kw1 + b) ----
    {
        f32x4 C = {0.f,0.f,0.f,0.f};
        C = gemm64(C, aST, wt + W_KW1, lm, kb8, cg);
        const float bv = kw1_b[cg];
#pragma unroll
        for (int rr = 0; rr < 4; ++rr) aH1[swz(kb8 * 4 + rr, cg)] = f2bf(leaky(C[rr] + bv));
    }
    __syncthreads();

    // ---- P2: KZ = H@kw2 + b ; H2 = leaky(ST@qw1 + b) ----
    {
        f32x4 C = {0.f,0.f,0.f,0.f};
        C = gemm64(C, aH1, wt + W_KW2, lm, kb8, cg);
        const float bv = kw2_b[cg];
#pragma unroll
        for (int rr = 0; rr < 4; ++rr) aKZ[swz(kb8 * 4 + rr, cg)] = f2bf(C[rr] + bv);
        f32x4 D = {0.f,0.f,0.f,0.f};
        D = gemm64(D, aST, wt + W_QW1, lm, kb8, cg);
        const float bq = qw1_b[cg];
#pragma unroll
        for (int rr = 0; rr < 4; ++rr) aH2[swz(kb8 * 4 + rr, cg)] = f2bf(leaky(D[rr] + bq));
    }
    __syncthreads();

    // ---- P3: QZ = H2@qw2 + b ----
    {
        f32x4 C = {0.f,0.f,0.f,0.f};
        C = gemm64(C, aH2, wt + W_QW2, lm, kb8, cg);
        const float bv = qw2_b[cg];
#pragma unroll
        for (int rr = 0; rr < 4; ++rr) aQZ[swz(kb8 * 4 + rr, cg)] = f2bf(C[rr] + bv);
    }
    __syncthreads();

    // ---- P4: wave0 diag(KZ@QZ^T) -> wzd ; waves 1,2 copy KZ/QZ -> global (swizzled bf16) ----
    if (jg == 0) {
        f32x4 C = {0.f,0.f,0.f,0.f};
#pragma unroll
        for (int k0 = 0; k0 < 64; k0 += 32) {
            const int g = (k0 >> 3) + kb8;
            const bf16x8 a  = *(const bf16x8*)&aKZ[lm * 64 + ((g ^ (lm & 7)) << 3)];
            const bf16x8 qb = *(const bf16x8*)&aQZ[lm * 64 + ((g ^ (lm & 7)) << 3)];
            C = __builtin_amdgcn_mfma_f32_16x16x32_bf16(a, qb, C, 0, 0, 0);
        }
        if ((lm >> 2) == kb8) wzd[lm] = 1.f / (1.f + __expf(-C[lm & 3] * 0.125f));
    } else if (jg == 1) {
        const u32* s = (const u32*)aKZ;
        for (int i = lane; i < 512; i += 64) kzg[blk * 512 + i] = s[i];
    } else if (jg == 2) {
        const u32* s = (const u32*)aQZ;
        for (int i = lane; i < 512; i += 64) qzg[blk * 512 + i] = s[i];
    }
    __syncthreads();

    // ---- P5: aP2 = z-part = wzd*act + (1-wzd)*pol ----
    {
        const int r2 = t >> 4, cc = t & 15;
        const float w = wzd[r2];
        aP2[swz32(r2, cc)] = f2bf(w * fACT[t] + (1.f - w) * fPOL[t]);
    }
    __syncthreads();

    // ---- P6: H = leaky(ST@ko1a + P2@ko1b + b) ----
    {
        f32x4 C = {0.f,0.f,0.f,0.f};
        C = gemm64(C, aST, wt + W_KO1A, lm, kb8, cg);
        C = gemm32(C, aP2, wt + W_KO1B, lm, kb8, cg);
        const float bv = ko1_b[cg];
#pragma unroll
        for (int rr = 0; rr < 4; ++rr) aH1[swz(kb8 * 4 + rr, cg)] = f2bf(leaky(C[rr] + bv));
    }
    __syncthreads();

    // ---- P7: KOBS = H@ko2 + b (bf16 + f32) ; aP2 <- pol-part ----
    {
        f32x4 C = {0.f,0.f,0.f,0.f};
        C = gemm64(C, aH1, wt + W_KO2, lm, kb8, cg);
        const float bv = ko2_b[cg];
#pragma unroll
        for (int rr = 0; rr < 4; ++rr) {
            const float v = C[rr] + bv;
            aH2[swz(kb8 * 4 + rr, cg)] = f2bf(v);
            fKOBS[(kb8 * 4 + rr) * 68 + cg] = v;
        }
        const int r2 = t >> 4, cc = t & 15;
        aP2[swz32(r2, cc)] = f2bf(fPOL[t]);
    }
    __syncthreads();

    // ---- P8: kq, kb, baseq, deltaq, basev(+repack), deltav, pre ----
    {
        f32x4 C = {0.f,0.f,0.f,0.f};
        C = gemm64(C, aH2, wt + W_QO2, lm, kb8, cg);   // kq = KOBS @ qo2_w^T (identity-oriented tile)
#pragma unroll
        for (int rr = 0; rr < 4; ++rr) kq[(row0 + kb8 * 4 + rr) * 64 + cg] = C[rr] * 0.125f;
    }
    {
        const float qb = qo2_b[lane];
#pragma unroll
        for (int q = 0; q < 4; ++q) {
            const int r = jg * 4 + q;
            const float s = wsum64(qb * fKOBS[r * 68 + lane]);
            if (lane == 0) kb[row0 + r] = s * 0.125f;
        }
    }
    {
        f32x4 C = {0.f,0.f,0.f,0.f};
        C = gemm64(C, aST, wt + W_QO1A, lm, kb8, cg);
        C = gemm32(C, aP2, wt + W_QO1B, lm, kb8, cg);
        const float bv = qo1_b[cg];
#pragma unroll
        for (int rr = 0; rr < 4; ++rr) baseq[(row0 + kb8 * 4 + rr) * 64 + cg] = C[rr] + bv;
    }
    {
        f32x4 C = {0.f,0.f,0.f,0.f};
        C = gemm32(C, aDAP, wt + W_QO1B, lm, kb8, cg);
#pragma unroll
        for (int rr = 0; rr < 4; ++rr) deltaq[(row0 + kb8 * 4 + rr) * 64 + cg] = C[rr];
    }
    {
        f32x4 C = {0.f,0.f,0.f,0.f};
        C = gemm64(C, aST, wt + W_AV1A, lm, kb8, cg);
        C = gemm32(C, aP2, wt + W_AV1B, lm, kb8, cg);
        const float bv = av1_b[cg];
#pragma unroll
        for (int rr = 0; rr < 4; ++rr) {
            const float v = C[rr] + bv;
            basev[(row0 + kb8 * 4 + rr) * 64 + cg] = v;
            aH1[swz(kb8 * 4 + rr, cg)] = f2bf(leaky(v));
        }
    }
    {
        f32x4 C = {0.f,0.f,0.f,0.f};
        C = gemm32(C, aDAP, wt + W_AV1B, lm, kb8, cg);
#pragma unroll
        for (int rr = 0; rr < 4; ++rr) deltav[(row0 + kb8 * 4 + rr) * 64 + cg] = C[rr];
    }
    {
        f32x4 C = {0.f,0.f,0.f,0.f};
        C = gemm64(C, aST, wt + W_FV1A, lm, kb8, cg);
        const float bv = fv1_b[cg];
#pragma unroll
        for (int rr = 0; rr < 4; ++rr) pre[(row0 + kb8 * 4 + rr) * 64 + cg] = C[rr] + bv;
    }
    __syncthreads();

    // ---- P9: vpf = leaky(basev)@M + c ----
    {
        f32x4 C = {0.f,0.f,0.f,0.f};
        C = gemm64(C, aH1, MT, lm, kb8, cg);
        const float bv = c_[cg];
#pragma unroll
        for (int rr = 0; rr < 4; ++rr) vpf[(row0 + kb8 * 4 + rr) * 64 + cg] = C[rr] + bv;
    }
}

// ---------------- kernel 2: per-(b,a-pair) main — 2 a's per block ----------------
__global__ __launch_bounds__(256)
void main_kernel(const u32* __restrict__ kzg,   const u32* __restrict__ qzg,
                 const float* __restrict__ kq,  const float* __restrict__ kb,
                 const float* __restrict__ baseq, const float* __restrict__ deltaq,
                 const float* __restrict__ basev, const float* __restrict__ deltav,
                 const float* __restrict__ pre,   const float* __restrict__ vpf,
                 const u16* __restrict__ MT,
                 const float* __restrict__ c,
                 const float* __restrict__ fv2_w, const float* __restrict__ fv2_b,
                 float* __restrict__ out_value,
                 float* __restrict__ out_wz,
                 float* __restrict__ out_wobs)
{
    const int bid0 = blockIdx.x;
    const int bid  = (bid0 & 7) * 256 + (bid0 >> 3);   // 2048 = 8*256; same-b blocks share XCD
    const int b = bid >> 4, a0 = (bid & 15) * 2;
    const int t = threadIdx.x, lane = t & 63, jg = t >> 6;
    const int row = t >> 3, s8 = t & 7, c0 = s8 * 8;

    __shared__ __align__(16) u16 sHV[2048];   // leaky(bv + wz*dv) bf16 swizzled [32][64]
    __shared__ float sC[32 * 65];             // C = HV@M, padded
    __shared__ float sHB[64];                 // hbar = sum_j w_j C_j
    __shared__ float s_sc[32];

    // ---- per-thread register slices: row (t>>3), cols c0..c0+7, shared across both a ----
    const int base = b * 2048 + t * 8;
    const float4 q0 = *(const float4*)&baseq[base],  q1 = *(const float4*)&baseq[base + 4];
    const float4 d0 = *(const float4*)&deltaq[base], d1 = *(const float4*)&deltaq[base + 4];
    const float4 v0 = *(const float4*)&basev[base],  v1 = *(const float4*)&basev[base + 4];
    const float4 e0 = *(const float4*)&deltav[base], e1 = *(const float4*)&deltav[base + 4];
    const float4 p0 = *(const float4*)&pre[base],    p1 = *(const float4*)&pre[base + 4];
    const float4 f0 = *(const float4*)&vpf[base],    f1 = *(const float4*)&vpf[base + 4];
    const float4 cc0 = *(const float4*)&c[c0],     cc1 = *(const float4*)&c[c0 + 4];
    const float4 fw0 = *(const float4*)&fv2_w[c0], fw1 = *(const float4*)&fv2_w[c0 + 4];
    const float fb2 = fv2_b[0];
    const float bqL[8] = {q0.x,q0.y,q0.z,q0.w,q1.x,q1.y,q1.z,q1.w};
    const float dqL[8] = {d0.x,d0.y,d0.z,d0.w,d1.x,d1.y,d1.z,d1.w};
    const float bvL[8] = {v0.x,v0.y,v0.z,v0.w,v1.x,v1.y,v1.z,v1.w};
    const float dvL[8] = {e0.x,e0.y,e0.z,e0.w,e1.x,e1.y,e1.z,e1.w};
    const float preL[8] = {p0.x,p0.y,p0.z,p0.w,p1.x,p1.y,p1.z,p1.w};
    const float vpfL[8] = {f0.x,f0.y,f0.z,f0.w,f1.x,f1.y,f1.z,f1.w};
    const float cL[8]  = {cc0.x,cc0.y,cc0.z,cc0.w,cc1.x,cc1.y,cc1.z,cc1.w};
    const float fwL[8] = {fw0.x,fw0.y,fw0.z,fw0.w,fw1.x,fw1.y,fw1.z,fw1.w};
    // qz fragment for this thread's row (a-independent)
    const int Gj = s8 ^ (row & 7);
    const u32* qzt = qzg + ((b * 2 + (row >> 4)) << 9) + ((row & 15) << 5) + (Gj << 2);
    const u32 qzu0 = qzt[0], qzu1 = qzt[1], qzu2 = qzt[2], qzu3 = qzt[3];

    for (int ai = 0; ai < 2; ++ai) {
        const int a = a0 + ai;

        // ---- P0: fused weight_z row ; scores ; HV build ----
        float wzv;
        {
            const int Ga = s8 ^ (a & 7);
            const u32* kzt = kzg + ((b * 2 + (a >> 4)) << 9) + ((a & 15) << 5) + (Ga << 2);
            float p = 0.f;
            const u32 qs[4] = {qzu0, qzu1, qzu2, qzu3};
#pragma unroll
            for (int e = 0; e < 4; ++e) {
                const u32 ku = kzt[e], qu = qs[e];
                p = fmaf(bf2f((short)(ku & 0xFFFF)), bf2f((short)(qu & 0xFFFF)), p);
                p = fmaf(bf2f((short)(ku >> 16)),   bf2f((short)(qu >> 16)),   p);
            }
            p += __shfl_xor(p, 1); p += __shfl_xor(p, 2); p += __shfl_xor(p, 4);
            wzv = 1.f / (1.f + __expf(-p * 0.125f));
            if (s8 == 0) out_wz[b * 1024 + a * 32 + row] = wzv;
        }
        {
            const float4 k0 = *(const float4*)&kq[(b * 32 + a) * 64 + c0];
            const float4 k1 = *(const float4*)&kq[(b * 32 + a) * 64 + c0 + 4];
            const float kqL[8] = {k0.x,k0.y,k0.z,k0.w,k1.x,k1.y,k1.z,k1.w};
            float p = 0.f;
#pragma unroll
            for (int e = 0; e < 8; ++e)
                p = fmaf(leaky(bqL[e] + wzv * dqL[e]), kqL[e], p);
            p += __shfl_xor(p, 1); p += __shfl_xor(p, 2); p += __shfl_xor(p, 4);
            if (s8 == 0) s_sc[row] = p + kb[b * 32 + a];
        }
        {
            float hv[8];
#pragma unroll
            for (int e = 0; e < 8; ++e) hv[e] = leaky(bvL[e] + wzv * dvL[e]);
            *(bf16x8*)&sHV[row * 64 + (Gj << 3)] = pack8(hv);
        }
        __syncthreads();   // bar1: s_sc + sHV visible

        // ---- P1: softmax ; C = HV@M via MFMA ; hbar from accumulators ----
        float wreg;
        {
            const float sreg = s_sc[lane & 31];
            float m = sreg;
#pragma unroll
            for (int o = 1; o < 32; o <<= 1) m = fmaxf(m, __shfl_xor(m, o));
            const float e = __expf(sreg - m);
            float ssum = e;
#pragma unroll
            for (int o = 1; o < 32; o <<= 1) ssum += __shfl_xor(ssum, o);
            wreg = e / ssum;
            if (t < 32) out_wobs[b * 1024 + a * 32 + t] = wreg;
        }
        {
            const int lm = lane & 15, kb8 = lane >> 4;
            const int bcol = jg * 16 + lm;
            f32x4 acc0 = {0.f,0.f,0.f,0.f}, acc1 = {0.f,0.f,0.f,0.f};
#pragma unroll
            for (int k0 = 0; k0 < 64; k0 += 32) {
                const int g = (k0 >> 3) + kb8;
                const bf16x8 bf = *(const bf16x8*)&MT[bcol * 64 + ((g ^ (bcol & 7)) << 3)];
                const bf16x8 A0 = *(const bf16x8*)&sHV[lm * 64 + ((g ^ (lm & 7)) << 3)];
                const bf16x8 A1 = *(const bf16x8*)&sHV[(16 + lm) * 64 + ((g ^ (lm & 7)) << 3)];
                acc0 = __builtin_amdgcn_mfma_f32_16x16x32_bf16(A0, bf, acc0, 0, 0, 0);
                acc1 = __builtin_amdgcn_mfma_f32_16x16x32_bf16(A1, bf, acc1, 0, 0, 0);
            }
            float hb = 0.f;
#pragma unroll
            for (int rr = 0; rr < 4; ++rr) {
                const int r0 = kb8 * 4 + rr, r1 = 16 + kb8 * 4 + rr;
                sC[r0 * 65 + bcol] = acc0[rr];
                sC[r1 * 65 + bcol] = acc1[rr];
                hb = fmaf(__shfl(wreg, r0), acc0[rr], hb);
                hb = fmaf(__shfl(wreg, r1), acc1[rr], hb);
            }
            hb += __shfl_xor(hb, 16);
            hb += __shfl_xor(hb, 32);
            if (lane < 16) sHB[bcol] = hb;
        }
        __syncthreads();   // bar2: sC + sHB visible

        // ---- P2: G in registers ; value via 8-lane reduce ----
        {
            const float wrow = __shfl(wreg, row);
            float vpart = 0.f;
#pragma unroll
            for (int e = 0; e < 8; ++e) {
                const int col = c0 + e;
                float g = preL[e] + (sHB[col] - wrow * sC[row * 65 + col]
                                     + (1.f - wrow) * cL[e] + wrow * vpfL[e]) * (1.f / 32.f);
                vpart = fmaf(leaky(g), fwL[e], vpart);
            }
            vpart += __shfl_xor(vpart, 1); vpart += __shfl_xor(vpart, 2); vpart += __shfl_xor(vpart, 4);
            if (s8 == 0) out_value[b * 1024 + a * 32 + row] = vpart + fb2;
        }
        // iter1's sHV/s_sc writes occur after bar2 (all P1 reads done);
        // iter1's sC/sHB writes occur after iter1's bar1 (all P2 reads done). Safe.
    }
}

extern "C" void kernel_launch(void* const* d_in, const int* in_sizes, int n_in,
                              void* d_out, int out_size, void* d_ws, size_t ws_size,
                              hipStream_t stream)
{
    const float* states   = (const float*)d_in[0];
    const float* policies = (const float*)d_in[1];
    const float* actions  = (const float*)d_in[2];
    const float* kw1_w = (const float*)d_in[3];  const float* kw1_b = (const float*)d_in[4];
    const float* kw2_w = (const float*)d_in[5];  const float* kw2_b = (const float*)d_in[6];
    const float* qw1_w = (const float*)d_in[7];  const float* qw1_b = (const float*)d_in[8];
    const float* qw2_w = (const float*)d_in[9];  const float* qw2_b = (const float*)d_in[10];
    const float* ko1_w = (const float*)d_in[11]; const float* ko1_b = (const float*)d_in[12];
    const float* ko2_w = (const float*)d_in[13]; const float* ko2_b = (const float*)d_in[14];
    const float* qo1_w = (const float*)d_in[15]; const float* qo1_b = (const float*)d_in[16];
    const float* qo2_w = (const float*)d_in[17]; const float* qo2_b = (const float*)d_in[18];
    const float* av1_w = (const float*)d_in[19]; const float* av1_b = (const float*)d_in[20];
    const float* av2_w = (const float*)d_in[21]; const float* av2_b = (const float*)d_in[22];
    const float* fv1_w = (const float*)d_in[23]; const float* fv1_b = (const float*)d_in[24];
    const float* fv2_w = (const float*)d_in[25]; const float* fv2_b = (const float*)d_in[26];

    float* out       = (float*)d_out;
    float* out_value = out;
    float* out_wz    = out + 131072;
    float* out_wobs  = out + 262144;

    const int SZ = 262144;                       // B*N*64 f32
    float* ws   = (float*)d_ws;
    float* c_   = ws;                            // 64
    float* kb_  = ws + 64;                       // 4096
    u16*   MT_  = (u16*)(ws + 4160);             // 4096 u16
    u32*   kzg  = (u32*)(ws + 6208);             // 131072 u32 (bf16 swz tiles)
    u32*   qzg  = (u32*)(ws + 137280);           // 131072 u32
    float* kq_   = ws + 268352;
    float* baseq = kq_   + SZ;
    float* dq_   = baseq + SZ;
    float* basev = dq_   + SZ;
    float* dv_   = basev + SZ;
    float* pre_  = dv_   + SZ;
    float* vpf_  = pre_  + SZ;
    u16*   wt_   = (u16*)(ws + 2103360);         // 47104 u16 weight arena (~8.5 MB total)

    prep_kernel<<<14, 256, 0, stream>>>(
        av2_w, av2_b, fv1_w,
        kw1_w, kw2_w, qw1_w, qw2_w, ko1_w, ko2_w, qo2_w, qo1_w, av1_w,
        MT_, c_, wt_);

    setup_kernel<<<256, 256, 0, stream>>>(
        states, policies, actions,
        kw1_b, kw2_b, qw1_b, qw2_b, ko1_b, ko2_b, qo1_b, qo2_b, av1_b, fv1_b,
        wt_, MT_, c_,
        kzg, qzg, kq_, kb_, baseq, dq_, basev, dv_, pre_, vpf_);

    main_kernel<<<2048, 256, 0, stream>>>(
        kzg, qzg, kq_, kb_, baseq, dq_, basev, dv_, pre_, vpf_,
        MT_, c_, fv2_w, fv2_b,
        out_value, out_wz, out_wobs);
}

// Round 14
// 38.241 us; speedup vs baseline: 1.1291x; 1.1291x over previous
//
#include <hip/hip_runtime.h>

#define NN   32
#define HID  64

typedef __attribute__((ext_vector_type(8))) short bf16x8;
typedef __attribute__((ext_vector_type(4))) float f32x4;
typedef unsigned short u16;
typedef unsigned int   u32;

__device__ __forceinline__ float leaky(float v) { return v >= 0.f ? v : 0.01f * v; }
__device__ __forceinline__ float wsum64(float p) {
#pragma unroll
    for (int o = 32; o; o >>= 1) p += __shfl_xor(p, o);
    return p;
}
__device__ __forceinline__ u16 f2bf(float f) {
    union { float f; u32 u; } v; v.f = f;
    return (u16)((v.u + 0x7FFFu + ((v.u >> 16) & 1)) >> 16);
}
__device__ __forceinline__ float bf2f(short s) {
    union { u32 u; float f; } v; v.u = ((u32)(u16)s) << 16;
    return v.f;
}
__device__ __forceinline__ bf16x8 pack8(const float* v) {
    bf16x8 r;
#pragma unroll
    for (int e = 0; e < 8; ++e) r[e] = (short)f2bf(v[e]);
    return r;
}
// swizzled offsets: [row][64] and [row][32] bf16 tiles
__device__ __forceinline__ int swz(int row, int col)   { return row * 64 + ((((col >> 3) ^ (row & 7)) << 3) | (col & 7)); }
__device__ __forceinline__ int swz32(int row, int col) { return row * 32 + ((((col >> 3) ^ (row & 3)) << 3) | (col & 7)); }

// C += A(16xK=64) @ W(cols): A,W both swizzled bf16 tiles (LDS or global)
__device__ __forceinline__ f32x4 gemm64(f32x4 C, const u16* A, const u16* W, int lm, int kb8, int bcol) {
#pragma unroll
    for (int k0 = 0; k0 < 64; k0 += 32) {
        const int g = (k0 >> 3) + kb8;
        const bf16x8 a = *(const bf16x8*)&A[lm * 64 + ((g ^ (lm & 7)) << 3)];
        const bf16x8 w = *(const bf16x8*)&W[bcol * 64 + ((g ^ (bcol & 7)) << 3)];
        C = __builtin_amdgcn_mfma_f32_16x16x32_bf16(a, w, C, 0, 0, 0);
    }
    return C;
}
// C += A(16xK=32) @ W  (K=32 part tiles, zero-padded)
__device__ __forceinline__ f32x4 gemm32(f32x4 C, const u16* A, const u16* W, int lm, int kb8, int bcol) {
    const bf16x8 a = *(const bf16x8*)&A[lm * 32 + ((kb8 ^ (lm & 3)) << 3)];
    const bf16x8 w = *(const bf16x8*)&W[bcol * 32 + ((kb8 ^ (bcol & 3)) << 3)];
    return __builtin_amdgcn_mfma_f32_16x16x32_bf16(a, w, C, 0, 0, 0);
}

// weight-tile offsets (u16 units) inside wt arena
#define W_KW1  0
#define W_KW2  4096
#define W_QW1  8192
#define W_QW2  12288
#define W_KO1A 16384
#define W_KO2  20480
#define W_QO2  24576
#define W_QO1A 28672
#define W_AV1A 32768
#define W_FV1A 36864
#define W_KO1B 40960
#define W_QO1B 43008
#define W_AV1B 45056

// ---------------- kernel 0: weight prep (bf16 swizzled W^T) + MT/c ----------------
__global__ __launch_bounds__(256)
void prep_kernel(const float* __restrict__ av2_w, const float* __restrict__ av2_b,
                 const float* __restrict__ fv1_w,
                 const float* __restrict__ kw1_w, const float* __restrict__ kw2_w,
                 const float* __restrict__ qw1_w, const float* __restrict__ qw2_w,
                 const float* __restrict__ ko1_w, const float* __restrict__ ko2_w,
                 const float* __restrict__ qo2_w, const float* __restrict__ qo1_w,
                 const float* __restrict__ av1_w,
                 u16* __restrict__ MT, float* __restrict__ c, u16* __restrict__ wt)
{
    const int blk = blockIdx.x, t = threadIdx.x;
    if (blk == 0) {
        // MT[h][k] = (av2_w @ fv1b)[k][h] bf16 swizzled ; c = av2_b @ fv1b
        const int h = t & 63, jg = t >> 6;
        __shared__ float sA[4096];
        for (int i = t; i < 4096; i += 256) sA[i] = av2_w[i];
        __syncthreads();
        const float* W = fv1_w + 4096;
        float acc[16];
#pragma unroll
        for (int i = 0; i < 16; ++i) acc[i] = 0.f;
        for (int m = 0; m < 64; ++m) {
            const float w = W[m * 64 + h];
#pragma unroll
            for (int i = 0; i < 16; ++i)
                acc[i] = fmaf(sA[(jg + 4 * i) * 64 + m], w, acc[i]);
        }
#pragma unroll
        for (int i = 0; i < 16; ++i) { const int k = jg + 4 * i; MT[swz(h, k)] = f2bf(acc[i]); }
        if (t < 64) {
            float s = 0.f;
            for (int m = 0; m < 64; ++m) s = fmaf(av2_b[m], W[m * 64 + t], s);
            c[t] = s;
        }
    } else if (blk <= 9) {
        // standard forward layers: Wtile[h][k] = W[k][h]  (transposed)
        const float* srcs[9] = {kw1_w, kw2_w, qw1_w, qw2_w, ko1_w, ko2_w, qo1_w, av1_w, fv1_w};
        const int    offs[9] = {W_KW1, W_KW2, W_QW1, W_QW2, W_KO1A, W_KO2, W_QO1A, W_AV1A, W_FV1A};
        const float* W = srcs[blk - 1]; u16* dst = wt + offs[blk - 1];
        for (int i = t; i < 4096; i += 256) { const int k = i >> 6, h = i & 63; dst[swz(h, k)] = f2bf(W[i]); }
    } else if (blk == 10) {
        // kq path needs the TRANSPOSED product: Wtile[h][d] = qo2_w[h][d]  (identity orientation)
        u16* dst = wt + W_QO2;
        for (int i = t; i < 4096; i += 256) { const int h = i >> 6, d = i & 63; dst[swz(h, d)] = f2bf(qo2_w[i]); }
    } else if (blk <= 13) {
        const float* srcs[3] = {ko1_w + 4096, qo1_w + 4096, av1_w + 4096};
        const int    offs[3] = {W_KO1B, W_QO1B, W_AV1B};
        const float* W = srcs[blk - 11]; u16* dst = wt + offs[blk - 11];
        for (int i = t; i < 1024; i += 256) {
            const int k = i >> 6, h = i & 63;
            dst[swz32(h, k)]      = f2bf(W[i]);
            dst[swz32(h, 16 + k)] = 0;
        }
    }
}

// ---------------- kernel 1: MFMA setup — split into 2 independent chains, 512 blocks ----------------
// blk <  256: chain A (wz-dependent): kz/qz/wzd/kobs -> kq, kb, kzg, qzg
// blk >= 256: chain B (wz-independent): baseq, deltaq, basev, deltav, pre, vpf
__global__ __launch_bounds__(256)
void setup_kernel(const float* __restrict__ states, const float* __restrict__ policies,
                  const float* __restrict__ actions,
                  const float* __restrict__ kw1_b, const float* __restrict__ kw2_b,
                  const float* __restrict__ qw1_b, const float* __restrict__ qw2_b,
                  const float* __restrict__ ko1_b, const float* __restrict__ ko2_b,
                  const float* __restrict__ qo1_b, const float* __restrict__ qo2_b,
                  const float* __restrict__ av1_b, const float* __restrict__ fv1_b,
                  const u16* __restrict__ wt, const u16* __restrict__ MT,
                  const float* __restrict__ c_,
                  u32* __restrict__ kzg, u32* __restrict__ qzg,
                  float* __restrict__ kq, float* __restrict__ kb,
                  float* __restrict__ baseq, float* __restrict__ deltaq,
                  float* __restrict__ basev, float* __restrict__ deltav,
                  float* __restrict__ pre, float* __restrict__ vpf)
{
    const int blk0 = blockIdx.x;
    const bool chainA = blk0 < 256;
    const int blk = chainA ? blk0 : blk0 - 256;
    const int row0 = blk * 16;
    const int t = threadIdx.x, lane = t & 63, jg = t >> 6;
    const int lm = lane & 15, kb8 = lane >> 4, cg = jg * 16 + lm;

    __shared__ __align__(16) u16 aST[1024], aH1[1024], aH2[1024], aKZ[1024], aQZ[1024];
    __shared__ __align__(16) u16 aP2[512], aDAP[512];
    __shared__ float fACT[256], fPOL[256];
    __shared__ float fKOBS[16 * 68];
    __shared__ float wzd[16];

    // ---- P0: stage inputs (both chains need ST; A needs ACT/POL; B needs POL/DAP) ----
    {
        const int i = t * 4, row = i >> 6, col = i & 63;
        const float4 s4 = *(const float4*)&states[row0 * 64 + i];
        const int base = swz(row, col);
        aST[base + 0] = f2bf(s4.x); aST[base + 1] = f2bf(s4.y);
        aST[base + 2] = f2bf(s4.z); aST[base + 3] = f2bf(s4.w);
        const float av = actions[row0 * 16 + t], pv = policies[row0 * 16 + t];
        fACT[t] = av; fPOL[t] = pv;
        const int r2 = t >> 4, cc = t & 15;
        aDAP[swz32(r2, cc)]      = f2bf(av - pv);
        aDAP[swz32(r2, 16 + cc)] = 0;
        aP2 [swz32(r2, 16 + cc)] = 0;
        if (!chainA) aP2[swz32(r2, cc)] = f2bf(pv);   // chain B: SP pol-part ready now
    }
    __syncthreads();

    if (chainA) {
        // ---- A1: H = leaky(ST@kw1 + b) ----
        {
            f32x4 C = {0.f,0.f,0.f,0.f};
            C = gemm64(C, aST, wt + W_KW1, lm, kb8, cg);
            const float bv = kw1_b[cg];
#pragma unroll
            for (int rr = 0; rr < 4; ++rr) aH1[swz(kb8 * 4 + rr, cg)] = f2bf(leaky(C[rr] + bv));
        }
        __syncthreads();
        // ---- A2: KZ = H@kw2 + b ; H2 = leaky(ST@qw1 + b) ----
        {
            f32x4 C = {0.f,0.f,0.f,0.f};
            C = gemm64(C, aH1, wt + W_KW2, lm, kb8, cg);
            const float bv = kw2_b[cg];
#pragma unroll
            for (int rr = 0; rr < 4; ++rr) aKZ[swz(kb8 * 4 + rr, cg)] = f2bf(C[rr] + bv);
            f32x4 D = {0.f,0.f,0.f,0.f};
            D = gemm64(D, aST, wt + W_QW1, lm, kb8, cg);
            const float bq = qw1_b[cg];
#pragma unroll
            for (int rr = 0; rr < 4; ++rr) aH2[swz(kb8 * 4 + rr, cg)] = f2bf(leaky(D[rr] + bq));
        }
        __syncthreads();
        // ---- A3: QZ = H2@qw2 + b ----
        {
            f32x4 C = {0.f,0.f,0.f,0.f};
            C = gemm64(C, aH2, wt + W_QW2, lm, kb8, cg);
            const float bv = qw2_b[cg];
#pragma unroll
            for (int rr = 0; rr < 4; ++rr) aQZ[swz(kb8 * 4 + rr, cg)] = f2bf(C[rr] + bv);
        }
        __syncthreads();
        // ---- A4: wave0 diag(KZ@QZ^T) -> wzd ; waves 1,2 copy KZ/QZ -> global ----
        if (jg == 0) {
            f32x4 C = {0.f,0.f,0.f,0.f};
#pragma unroll
            for (int k0 = 0; k0 < 64; k0 += 32) {
                const int g = (k0 >> 3) + kb8;
                const bf16x8 a  = *(const bf16x8*)&aKZ[lm * 64 + ((g ^ (lm & 7)) << 3)];
                const bf16x8 qb = *(const bf16x8*)&aQZ[lm * 64 + ((g ^ (lm & 7)) << 3)];
                C = __builtin_amdgcn_mfma_f32_16x16x32_bf16(a, qb, C, 0, 0, 0);
            }
            if ((lm >> 2) == kb8) wzd[lm] = 1.f / (1.f + __expf(-C[lm & 3] * 0.125f));
        } else if (jg == 1) {
            const u32* s = (const u32*)aKZ;
            for (int i = lane; i < 512; i += 64) kzg[blk * 512 + i] = s[i];
        } else if (jg == 2) {
            const u32* s = (const u32*)aQZ;
            for (int i = lane; i < 512; i += 64) qzg[blk * 512 + i] = s[i];
        }
        __syncthreads();
        // ---- A5: aP2 = z-part = wzd*act + (1-wzd)*pol ----
        {
            const int r2 = t >> 4, cc = t & 15;
            const float w = wzd[r2];
            aP2[swz32(r2, cc)] = f2bf(w * fACT[t] + (1.f - w) * fPOL[t]);
        }
        __syncthreads();
        // ---- A6: H = leaky(ST@ko1a + P2@ko1b + b) ----
        {
            f32x4 C = {0.f,0.f,0.f,0.f};
            C = gemm64(C, aST, wt + W_KO1A, lm, kb8, cg);
            C = gemm32(C, aP2, wt + W_KO1B, lm, kb8, cg);
            const float bv = ko1_b[cg];
#pragma unroll
            for (int rr = 0; rr < 4; ++rr) aH1[swz(kb8 * 4 + rr, cg)] = f2bf(leaky(C[rr] + bv));
        }
        __syncthreads();
        // ---- A7: KOBS = H@ko2 + b ----
        {
            f32x4 C = {0.f,0.f,0.f,0.f};
            C = gemm64(C, aH1, wt + W_KO2, lm, kb8, cg);
            const float bv = ko2_b[cg];
#pragma unroll
            for (int rr = 0; rr < 4; ++rr) {
                const float v = C[rr] + bv;
                aH2[swz(kb8 * 4 + rr, cg)] = f2bf(v);
                fKOBS[(kb8 * 4 + rr) * 68 + cg] = v;
            }
        }
        __syncthreads();
        // ---- A8: kq = KOBS @ qo2_w^T ; kb ----
        {
            f32x4 C = {0.f,0.f,0.f,0.f};
            C = gemm64(C, aH2, wt + W_QO2, lm, kb8, cg);
#pragma unroll
            for (int rr = 0; rr < 4; ++rr) kq[(row0 + kb8 * 4 + rr) * 64 + cg] = C[rr] * 0.125f;
        }
        {
            const float qb = qo2_b[lane];
#pragma unroll
            for (int q = 0; q < 4; ++q) {
                const int r = jg * 4 + q;
                const float s = wsum64(qb * fKOBS[r * 68 + lane]);
                if (lane == 0) kb[row0 + r] = s * 0.125f;
            }
        }
    } else {
        // ================= chain B (no wz dependence) =================
        // ---- B1: baseq = ST@qo1a + POL@qo1b + b ; deltaq = dAP@qo1b ----
        {
            f32x4 C = {0.f,0.f,0.f,0.f};
            C = gemm64(C, aST, wt + W_QO1A, lm, kb8, cg);
            C = gemm32(C, aP2, wt + W_QO1B, lm, kb8, cg);
            const float bv = qo1_b[cg];
#pragma unroll
            for (int rr = 0; rr < 4; ++rr) baseq[(row0 + kb8 * 4 + rr) * 64 + cg] = C[rr] + bv;
        }
        {
            f32x4 C = {0.f,0.f,0.f,0.f};
            C = gemm32(C, aDAP, wt + W_QO1B, lm, kb8, cg);
#pragma unroll
            for (int rr = 0; rr < 4; ++rr) deltaq[(row0 + kb8 * 4 + rr) * 64 + cg] = C[rr];
        }
        // ---- B2: basev (+leaky repack to aH1) ; deltav ; pre ----
        {
            f32x4 C = {0.f,0.f,0.f,0.f};
            C = gemm64(C, aST, wt + W_AV1A, lm, kb8, cg);
            C = gemm32(C, aP2, wt + W_AV1B, lm, kb8, cg);
            const float bv = av1_b[cg];
#pragma unroll
            for (int rr = 0; rr < 4; ++rr) {
                const float v = C[rr] + bv;
                basev[(row0 + kb8 * 4 + rr) * 64 + cg] = v;
                aH1[swz(kb8 * 4 + rr, cg)] = f2bf(leaky(v));
            }
        }
        {
            f32x4 C = {0.f,0.f,0.f,0.f};
            C = gemm32(C, aDAP, wt + W_AV1B, lm, kb8, cg);
#pragma unroll
            for (int rr = 0; rr < 4; ++rr) deltav[(row0 + kb8 * 4 + rr) * 64 + cg] = C[rr];
        }
        {
            f32x4 C = {0.f,0.f,0.f,0.f};
            C = gemm64(C, aST, wt + W_FV1A, lm, kb8, cg);
            const float bv = fv1_b[cg];
#pragma unroll
            for (int rr = 0; rr < 4; ++rr) pre[(row0 + kb8 * 4 + rr) * 64 + cg] = C[rr] + bv;
        }
        __syncthreads();
        // ---- B3: vpf = leaky(basev)@M + c ----
        {
            f32x4 C = {0.f,0.f,0.f,0.f};
            C = gemm64(C, aH1, MT, lm, kb8, cg);
            const float bv = c_[cg];
#pragma unroll
            for (int rr = 0; rr < 4; ++rr) vpf[(row0 + kb8 * 4 + rr) * 64 + cg] = C[rr] + bv;
        }
    }
}

// ---------------- kernel 2: per-(b,a) main — R12 exact (2 barriers, wz fused) ----------------
__global__ __launch_bounds__(256)
void main_kernel(const u32* __restrict__ kzg,   const u32* __restrict__ qzg,
                 const float* __restrict__ kq,  const float* __restrict__ kb,
                 const float* __restrict__ baseq, const float* __restrict__ deltaq,
                 const float* __restrict__ basev, const float* __restrict__ deltav,
                 const float* __restrict__ pre,   const float* __restrict__ vpf,
                 const u16* __restrict__ MT,
                 const float* __restrict__ c,
                 const float* __restrict__ fv2_w, const float* __restrict__ fv2_b,
                 float* __restrict__ out_value,
                 float* __restrict__ out_wz,
                 float* __restrict__ out_wobs)
{
    const int bid0 = blockIdx.x;
    const int bid  = (bid0 & 7) * 512 + (bid0 >> 3);   // XCD swizzle; same-b blocks share XCD
    const int b = bid >> 5, a = bid & 31;
    const int t = threadIdx.x, lane = t & 63, jg = t >> 6;
    const int row = t >> 3, s8 = t & 7, c0 = s8 * 8;

    __shared__ __align__(16) u16 sHV[2048];   // leaky(bv + wz*dv) bf16 swizzled [32][64]
    __shared__ float sC[32 * 65];             // C = HV@M, padded
    __shared__ float sHB[64];                 // hbar = sum_j w_j C_j
    __shared__ float s_sc[32];

    // ---- P0: fused weight_z row; scores via 8-lane reduce ; HV build ; prefetch pre/vpf ----
    const int base = b * 2048 + t * 8;
    const float kbv = kb[b * 32 + a];
    const float4 p0 = *(const float4*)&pre[base], p1 = *(const float4*)&pre[base + 4];
    const float4 f0 = *(const float4*)&vpf[base], f1 = *(const float4*)&vpf[base + 4];

    // wz[b,a,row] = sigmoid(kz[a].qz[row]/8), computed from bf16 swizzled tiles in L2
    float wzv;
    {
        const int Ga = s8 ^ (a & 7);
        const u32* kzt = kzg + ((b * 2 + (a >> 4)) << 9) + ((a & 15) << 5) + (Ga << 2);
        const int Gj = s8 ^ (row & 7);
        const u32* qzt = qzg + ((b * 2 + (row >> 4)) << 9) + ((row & 15) << 5) + (Gj << 2);
        float p = 0.f;
#pragma unroll
        for (int e = 0; e < 4; ++e) {
            const u32 ku = kzt[e], qu = qzt[e];
            p = fmaf(bf2f((short)(ku & 0xFFFF)), bf2f((short)(qu & 0xFFFF)), p);
            p = fmaf(bf2f((short)(ku >> 16)),   bf2f((short)(qu >> 16)),   p);
        }
        p += __shfl_xor(p, 1); p += __shfl_xor(p, 2); p += __shfl_xor(p, 4);
        wzv = 1.f / (1.f + __expf(-p * 0.125f));
        if (s8 == 0) out_wz[b * 1024 + a * 32 + row] = wzv;
    }
    {
        const float4 q0 = *(const float4*)&baseq[base],  q1 = *(const float4*)&baseq[base + 4];
        const float4 d0 = *(const float4*)&deltaq[base], d1 = *(const float4*)&deltaq[base + 4];
        const float4 k0 = *(const float4*)&kq[(b * 32 + a) * 64 + c0];
        const float4 k1 = *(const float4*)&kq[(b * 32 + a) * 64 + c0 + 4];
        float p = leaky(q0.x + wzv * d0.x) * k0.x;
        p = fmaf(leaky(q0.y + wzv * d0.y), k0.y, p);
        p = fmaf(leaky(q0.z + wzv * d0.z), k0.z, p);
        p = fmaf(leaky(q0.w + wzv * d0.w), k0.w, p);
        p = fmaf(leaky(q1.x + wzv * d1.x), k1.x, p);
        p = fmaf(leaky(q1.y + wzv * d1.y), k1.y, p);
        p = fmaf(leaky(q1.z + wzv * d1.z), k1.z, p);
        p = fmaf(leaky(q1.w + wzv * d1.w), k1.w, p);
        p += __shfl_xor(p, 1); p += __shfl_xor(p, 2); p += __shfl_xor(p, 4);
        if (s8 == 0) s_sc[row] = p + kbv;
    }
    {
        const float4 v0 = *(const float4*)&basev[base],  v1 = *(const float4*)&basev[base + 4];
        const float4 e0 = *(const float4*)&deltav[base], e1 = *(const float4*)&deltav[base + 4];
        float hv[8];
        hv[0]=leaky(v0.x+wzv*e0.x); hv[1]=leaky(v0.y+wzv*e0.y); hv[2]=leaky(v0.z+wzv*e0.z); hv[3]=leaky(v0.w+wzv*e0.w);
        hv[4]=leaky(v1.x+wzv*e1.x); hv[5]=leaky(v1.y+wzv*e1.y); hv[6]=leaky(v1.z+wzv*e1.z); hv[7]=leaky(v1.w+wzv*e1.w);
        const int g2 = s8 ^ (row & 7);
        *(bf16x8*)&sHV[row * 64 + (g2 << 3)] = pack8(hv);
    }
    __syncthreads();

    // ---- P1: softmax (in-register, all waves) ; C = HV@M via MFMA ; hbar from accs ----
    float wreg;
    {
        const float sreg = s_sc[lane & 31];
        float m = sreg;
#pragma unroll
        for (int o = 1; o < 32; o <<= 1) m = fmaxf(m, __shfl_xor(m, o));
        const float e = __expf(sreg - m);
        float ssum = e;
#pragma unroll
        for (int o = 1; o < 32; o <<= 1) ssum += __shfl_xor(ssum, o);
        wreg = e / ssum;
        if (t < 32) out_wobs[b * 1024 + a * 32 + t] = wreg;
    }
    {
        const int lm = lane & 15, kb8 = lane >> 4;
        const int bcol = jg * 16 + lm;
        f32x4 acc0 = {0.f,0.f,0.f,0.f}, acc1 = {0.f,0.f,0.f,0.f};
#pragma unroll
        for (int k0 = 0; k0 < 64; k0 += 32) {
            const int g = (k0 >> 3) + kb8;
            const bf16x8 bf = *(const bf16x8*)&MT[bcol * 64 + (((g ^ (bcol & 7)) << 3))];
            const int r0 = lm, r1 = 16 + lm;
            const bf16x8 a0 = *(const bf16x8*)&sHV[r0 * 64 + (((g ^ (r0 & 7)) << 3))];
            const bf16x8 a1 = *(const bf16x8*)&sHV[r1 * 64 + (((g ^ (r1 & 7)) << 3))];
            acc0 = __builtin_amdgcn_mfma_f32_16x16x32_bf16(a0, bf, acc0, 0, 0, 0);
            acc1 = __builtin_amdgcn_mfma_f32_16x16x32_bf16(a1, bf, acc1, 0, 0, 0);
        }
        float hb = 0.f;
#pragma unroll
        for (int rr = 0; rr < 4; ++rr) {
            const int r0 = kb8 * 4 + rr, r1 = 16 + kb8 * 4 + rr;
            sC[r0 * 65 + bcol] = acc0[rr];
            sC[r1 * 65 + bcol] = acc1[rr];
            hb = fmaf(__shfl(wreg, r0), acc0[rr], hb);
            hb = fmaf(__shfl(wreg, r1), acc1[rr], hb);
        }
        hb += __shfl_xor(hb, 16);
        hb += __shfl_xor(hb, 32);
        if (lane < 16) sHB[bcol] = hb;
    }
    __syncthreads();

    // ---- P2: G in registers ; value via 8-lane reduce ----
    {
        const float wrow = __shfl(wreg, row);   // lane `row` (<32) holds w[row]
        const float4 cc0 = *(const float4*)&c[c0],     cc1 = *(const float4*)&c[c0 + 4];
        const float4 fw0 = *(const float4*)&fv2_w[c0], fw1 = *(const float4*)&fv2_w[c0 + 4];
        const float preL[8] = {p0.x,p0.y,p0.z,p0.w,p1.x,p1.y,p1.z,p1.w};
        const float vpfL[8] = {f0.x,f0.y,f0.z,f0.w,f1.x,f1.y,f1.z,f1.w};
        const float cL[8]   = {cc0.x,cc0.y,cc0.z,cc0.w,cc1.x,cc1.y,cc1.z,cc1.w};
        const float fwL[8]  = {fw0.x,fw0.y,fw0.z,fw0.w,fw1.x,fw1.y,fw1.z,fw1.w};
        float vpart = 0.f;
#pragma unroll
        for (int e = 0; e < 8; ++e) {
            const int col = c0 + e;
            float g = preL[e] + (sHB[col] - wrow * sC[row * 65 + col]
                                 + (1.f - wrow) * cL[e] + wrow * vpfL[e]) * (1.f / 32.f);
            g = leaky(g);
            vpart = fmaf(g, fwL[e], vpart);
        }
        vpart += __shfl_xor(vpart, 1); vpart += __shfl_xor(vpart, 2); vpart += __shfl_xor(vpart, 4);
        if (s8 == 0) out_value[b * 1024 + a * 32 + row] = vpart + fv2_b[0];
    }
}

extern "C" void kernel_launch(void* const* d_in, const int* in_sizes, int n_in,
                              void* d_out, int out_size, void* d_ws, size_t ws_size,
                              hipStream_t stream)
{
    const float* states   = (const float*)d_in[0];
    const float* policies = (const float*)d_in[1];
    const float* actions  = (const float*)d_in[2];
    const float* kw1_w = (const float*)d_in[3];  const float* kw1_b = (const float*)d_in[4];
    const float* kw2_w = (const float*)d_in[5];  const float* kw2_b = (const float*)d_in[6];
    const float* qw1_w = (const float*)d_in[7];  const float* qw1_b = (const float*)d_in[8];
    const float* qw2_w = (const float*)d_in[9];  const float* qw2_b = (const float*)d_in[10];
    const float* ko1_w = (const float*)d_in[11]; const float* ko1_b = (const float*)d_in[12];
    const float* ko2_w = (const float*)d_in[13]; const float* ko2_b = (const float*)d_in[14];
    const float* qo1_w = (const float*)d_in[15]; const float* qo1_b = (const float*)d_in[16];
    const float* qo2_w = (const float*)d_in[17]; const float* qo2_b = (const float*)d_in[18];
    const float* av1_w = (const float*)d_in[19]; const float* av1_b = (const float*)d_in[20];
    const float* av2_w = (const float*)d_in[21]; const float* av2_b = (const float*)d_in[22];
    const float* fv1_w = (const float*)d_in[23]; const float* fv1_b = (const float*)d_in[24];
    const float* fv2_w = (const float*)d_in[25]; const float* fv2_b = (const float*)d_in[26];

    float* out       = (float*)d_out;
    float* out_value = out;
    float* out_wz    = out + 131072;
    float* out_wobs  = out + 262144;

    const int SZ = 262144;                       // B*N*64 f32
    float* ws   = (float*)d_ws;
    float* c_   = ws;                            // 64
    float* kb_  = ws + 64;                       // 4096
    u16*   MT_  = (u16*)(ws + 4160);             // 4096 u16
    u32*   kzg  = (u32*)(ws + 6208);             // 131072 u32 (bf16 swz tiles)
    u32*   qzg  = (u32*)(ws + 137280);           // 131072 u32
    float* kq_   = ws + 268352;
    float* baseq = kq_   + SZ;
    float* dq_   = baseq + SZ;
    float* basev = dq_   + SZ;
    float* dv_   = basev + SZ;
    float* pre_  = dv_   + SZ;
    float* vpf_  = pre_  + SZ;
    u16*   wt_   = (u16*)(ws + 2103360);         // 47104 u16 weight arena (~8.5 MB total)

    prep_kernel<<<14, 256, 0, stream>>>(
        av2_w, av2_b, fv1_w,
        kw1_w, kw2_w, qw1_w, qw2_w, ko1_w, ko2_w, qo2_w, qo1_w, av1_w,
        MT_, c_, wt_);

    setup_kernel<<<512, 256, 0, stream>>>(
        states, policies, actions,
        kw1_b, kw2_b, qw1_b, qw2_b, ko1_b, ko2_b, qo1_b, qo2_b, av1_b, fv1_b,
        wt_, MT_, c_,
        kzg, qzg, kq_, kb_, baseq, dq_, basev, dv_, pre_, vpf_);

    main_kernel<<<4096, 256, 0, stream>>>(
        kzg, qzg, kq_, kb_, baseq, dq_, basev, dv_, pre_, vpf_,
        MT_, c_, fv2_w, fv2_b,
        out_value, out_wz, out_wobs);
}